// Round 2
// baseline (196.889 us; speedup 1.0000x reference)
//
#include <hip/hip_runtime.h>
#include <hip/hip_bf16.h>

// Problem: B=2, S=2048, D=1024, H=16, dh=64. Inputs fp32, output FP32.
// Round 14: bisect of R13's numerics failure (8.5e-2 absmax).
//  KEEP from R13 (verified-by-derivation, structural wins):
//   - Pipelined k-loop: K/V double-buffered in LDS; tile kt+1's DMA issued
//     BEFORE compute of tile kt; one __syncthreads per tile (its vmcnt(0)
//     drain = prefetch completion, landing after a full compute phase).
//   - 128 q-rows per block (8 waves, 512 thr): halves per-compute K/V DMA,
//     16 blocks share each (b,h) K/V stream instead of 32.
//  REVERT from R13 (correctness suspects):
//   - P->bf16 back to scalar f2bf RNE (m240: hand-written cvt_pk is -37%
//     anyway); Ps back to R12's [16][66] odd-dword-stride layout.
//   - wave_barrier alone is NOT a compiler memory fence -> replaced with
//     s_waitcnt lgkmcnt(0) + sched_barrier(0): hard W->R order on Ps.
// R12 (verified): 202.2 us total. R11 attn: MfmaUtil 8.9%.

typedef __attribute__((ext_vector_type(8))) short bf16x8;
typedef __attribute__((ext_vector_type(4))) float f32x4;
typedef __attribute__((ext_vector_type(4))) int int4v;

#define MFMA16(A, B, C) __builtin_amdgcn_mfma_f32_16x16x32_bf16((A), (B), (C), 0, 0, 0)

#if __has_builtin(__builtin_amdgcn_exp2f)
#define EXP2(x) __builtin_amdgcn_exp2f(x)
#else
#define EXP2(x) exp2f(x)
#endif

static __device__ __forceinline__ unsigned short f2bf(float f) {
    union { float f; unsigned int u; } v;
    v.f = f;
    unsigned int u = v.u;
    u += ((u >> 16) & 1u) + 0x7FFFu;   // RNE
    return (unsigned short)(u >> 16);
}

// async global->LDS DMA, 16B per lane; LDS dest = uniform base + lane*16
static __device__ __forceinline__ void gload_lds16(const void* g, void* l) {
    __builtin_amdgcn_global_load_lds(
        (const __attribute__((address_space(1))) void*)g,
        (__attribute__((address_space(3))) void*)l, 16, 0, 0);
}

// ---------------------------------------------------------------------------
// Pre-pass 1: cast hs fp32 -> bf16. 8 elems/thread.
// ---------------------------------------------------------------------------
__global__ __launch_bounds__(256) void cast_hs(const float* __restrict__ in,
                                               unsigned short* __restrict__ out) {
    const size_t i = ((size_t)blockIdx.x * 256 + threadIdx.x) * 8;
    float4 a0 = *reinterpret_cast<const float4*>(in + i);
    float4 a1 = *reinterpret_cast<const float4*>(in + i + 4);
    unsigned short t[8];
    t[0] = f2bf(a0.x); t[1] = f2bf(a0.y); t[2] = f2bf(a0.z); t[3] = f2bf(a0.w);
    t[4] = f2bf(a1.x); t[5] = f2bf(a1.y); t[6] = f2bf(a1.z); t[7] = f2bf(a1.w);
    *reinterpret_cast<int4v*>(out + i) = *reinterpret_cast<int4v*>(t);
}

// ---------------------------------------------------------------------------
// Pre-pass 2: W[1024][1024] fp32 -> Wt[n][k] bf16 (3 slices via grid.z).
// ---------------------------------------------------------------------------
__global__ __launch_bounds__(256) void transpose_cast_w(
    const float* __restrict__ W0, const float* __restrict__ W1,
    const float* __restrict__ W2, unsigned short* __restrict__ Wt) {
    __shared__ float Ts[64][65];
    const float* W = (blockIdx.z == 0) ? W0 : (blockIdx.z == 1) ? W1 : W2;
    unsigned short* O = Wt + (size_t)blockIdx.z * 1048576;

    const int t  = threadIdx.x;
    const int k0 = blockIdx.y * 64;
    const int n0 = blockIdx.x * 64;

    {
        const int kr = t >> 2, nc = (t & 3) * 16;
        const float* p = W + (size_t)(k0 + kr) * 1024 + n0 + nc;
        float4 r0 = *reinterpret_cast<const float4*>(p);
        float4 r1 = *reinterpret_cast<const float4*>(p + 4);
        float4 r2 = *reinterpret_cast<const float4*>(p + 8);
        float4 r3 = *reinterpret_cast<const float4*>(p + 12);
        float* d = &Ts[kr][nc];
        d[0]=r0.x; d[1]=r0.y; d[2]=r0.z; d[3]=r0.w;
        d[4]=r1.x; d[5]=r1.y; d[6]=r1.z; d[7]=r1.w;
        d[8]=r2.x; d[9]=r2.y; d[10]=r2.z; d[11]=r2.w;
        d[12]=r3.x; d[13]=r3.y; d[14]=r3.z; d[15]=r3.w;
    }
    __syncthreads();
    {
        const int nr = t >> 2, kc = (t & 3) * 16;
        unsigned short tmp[16];
#pragma unroll
        for (int i = 0; i < 16; i++) tmp[i] = f2bf(Ts[kc + i][nr]);
        unsigned short* d = O + (size_t)(n0 + nr) * 1024 + k0 + kc;
        *reinterpret_cast<int4v*>(d)     = *reinterpret_cast<int4v*>(&tmp[0]);
        *reinterpret_cast<int4v*>(d + 8) = *reinterpret_cast<int4v*>(&tmp[8]);
    }
}

// ---------------------------------------------------------------------------
// Kernel 3: QKV GEMM (m97 pattern, DMA staging, 128x128, BK=32).
// Epilogues: z=0 Q natural layout, PRE-SCALED by 0.125*log2(e);
//            z=1 K swizzled cols (d-chunk ^ (s&7));
//            z=2 V^T [B,H,dh,S] swizzled cols (s-chunk ^ (d&7)).
// ---------------------------------------------------------------------------
__global__ __launch_bounds__(256) void qkv_gemm_dma(
    const unsigned short* __restrict__ hsb,
    const unsigned short* __restrict__ Wt,
    const float* __restrict__ b0, const float* __restrict__ b1,
    const float* __restrict__ b2,
    unsigned short* __restrict__ Qo,
    unsigned short* __restrict__ Ko,
    unsigned short* __restrict__ Vto)
{
    __shared__ unsigned short As[128][32];
    __shared__ unsigned short Bs[128][32];

    const int z = blockIdx.z;
    const unsigned short* W = Wt + (size_t)z * 1048576;
    const float* bias = (z == 0) ? b0 : (z == 1) ? b1 : b2;

    const int tid  = threadIdx.x;
    const int lane = tid & 63;
    const int w    = tid >> 6;
    const int l15  = lane & 15;
    const int quad = lane >> 4;
    const int m0   = blockIdx.y * 128;
    const int n0   = blockIdx.x * 128;
    const int wm   = (w >> 1) * 64;
    const int wn   = (w & 1) * 64;

    const int drow = lane >> 2;
    const int dcol = (lane & 3) * 8;

    f32x4 acc[4][4];
#pragma unroll
    for (int i = 0; i < 4; i++)
#pragma unroll
        for (int j = 0; j < 4; j++)
            acc[i][j] = (f32x4){0.f, 0.f, 0.f, 0.f};

    for (int k0 = 0; k0 < 1024; k0 += 32) {
        __syncthreads();
#pragma unroll
        for (int p = 0; p < 2; p++) {
            const int s = w * 2 + p;
            gload_lds16(hsb + (size_t)(m0 + s * 16 + drow) * 1024 + k0 + dcol,
                        &As[s * 16][0]);
            gload_lds16(W   + (size_t)(n0 + s * 16 + drow) * 1024 + k0 + dcol,
                        &Bs[s * 16][0]);
        }
        __syncthreads();

        bf16x8 af[4], bfr[4];
#pragma unroll
        for (int i = 0; i < 4; i++)
            af[i] = *reinterpret_cast<const bf16x8*>(&As[wm + i * 16 + l15][quad * 8]);
#pragma unroll
        for (int j = 0; j < 4; j++)
            bfr[j] = *reinterpret_cast<const bf16x8*>(&Bs[wn + j * 16 + l15][quad * 8]);
#pragma unroll
        for (int i = 0; i < 4; i++)
#pragma unroll
            for (int j = 0; j < 4; j++)
                acc[i][j] = MFMA16(af[i], bfr[j], acc[i][j]);
    }

    if (z == 0) {
        // Q: natural [B,H,S,dh], pre-scaled by 0.125*log2(e)
        const float qs = 0.18033688f;
#pragma unroll
        for (int i = 0; i < 4; i++) {
            const int mbase = m0 + wm + i * 16 + quad * 4;
#pragma unroll
            for (int j = 0; j < 4; j++) {
                const int n = n0 + wn + j * 16 + l15;
                const int h = n >> 6, d = n & 63;
                const float bn = bias[n];
#pragma unroll
                for (int r = 0; r < 4; r++) {
                    const int mm = mbase + r;
                    const int b = mm >> 11, s = mm & 2047;
                    Qo[(((size_t)(b * 16 + h) * 2048 + s) * 64) + d] =
                        f2bf((acc[i][j][r] + bn) * qs);
                }
            }
        }
    } else if (z == 1) {
        // K: [B,H,S,dh] with d-chunk swizzle by (s&7)
#pragma unroll
        for (int i = 0; i < 4; i++) {
            const int mbase = m0 + wm + i * 16 + quad * 4;
#pragma unroll
            for (int j = 0; j < 4; j++) {
                const int n = n0 + wn + j * 16 + l15;
                const int h = n >> 6, d = n & 63;
                const float bn = bias[n];
#pragma unroll
                for (int r = 0; r < 4; r++) {
                    const int mm = mbase + r;
                    const int b = mm >> 11, s = mm & 2047;
                    const int dsw = ((((d >> 3) ^ (s & 7)) & 7) << 3) | (d & 7);
                    Ko[(((size_t)(b * 16 + h) * 2048 + s) * 64) + dsw] =
                        f2bf(acc[i][j][r] + bn);
                }
            }
        }
    } else {
        // V^T: [B,H,dh,S] with s-chunk swizzle by (d&7); 4 consecutive s packed
#pragma unroll
        for (int i = 0; i < 4; i++) {
            const int mbase = m0 + wm + i * 16 + quad * 4;
            const int b = mbase >> 11, s0 = mbase & 2047;
#pragma unroll
            for (int j = 0; j < 4; j++) {
                const int n = n0 + wn + j * 16 + l15;
                const int h = n >> 6, d = n & 63;
                const float bn = bias[n];
                ushort4 v4;
                v4.x = f2bf(acc[i][j][0] + bn);
                v4.y = f2bf(acc[i][j][1] + bn);
                v4.z = f2bf(acc[i][j][2] + bn);
                v4.w = f2bf(acc[i][j][3] + bn);
                const int cs  = (s0 & 63) >> 3;
                const int ssw = (s0 & ~63) | (((cs ^ (d & 7)) & 7) << 3) | (s0 & 7);
                *reinterpret_cast<ushort4*>(
                    Vto + ((size_t)(b * 16 + h) * 64 + d) * 2048 + ssw) = v4;
            }
        }
    }
}

// ---------------------------------------------------------------------------
// Kernel 4: MFMA flash attention, max-free softmax, swizzled K/V^T tiles.
// 1 block = (b,h,128 q-rows), 8 waves; wave w owns q-rows [16w,16w+16).
// Pipelined: K/V double-buffered, next tile's DMA issued before compute,
// one __syncthreads per tile (its vmcnt drain = prefetch completion).
// P path identical to verified R12 (f2bf scalar, Ps[16][66] linear).
// ---------------------------------------------------------------------------
__global__ __launch_bounds__(512) void attn3(
    const unsigned short* __restrict__ Qg,
    const unsigned short* __restrict__ Kg,
    const unsigned short* __restrict__ Vtg,
    float* __restrict__ out)
{
    __shared__ unsigned short Ks[2][64][64];   // [buf][kk][d] swizzled (DMA)
    __shared__ unsigned short Vs[2][64][64];   // [buf] V^T tile [d][kk] swizzled (DMA)
    __shared__ unsigned short Ps[8][16][66];   // per-wave P [qrow][kk], pad 66

    const int tid  = threadIdx.x;
    const int lane = tid & 63;
    const int w    = tid >> 6;        // 0..7
    const int l15  = lane & 15;
    const int quad = lane >> 4;

    const int q0 = blockIdx.x * 128;
    const int h  = blockIdx.y;
    const int b  = blockIdx.z;
    const size_t base = (size_t)(b * 16 + h) * 2048 * 64;
    const unsigned short* Qh  = Qg  + base;
    const unsigned short* Kh  = Kg  + base;
    const unsigned short* Vth = Vtg + base;

    const int drow = lane >> 3;       // 0..7
    const int dcol = (lane & 7) * 8;  // 0..56

    bf16x8 qf[2];
#pragma unroll
    for (int ks = 0; ks < 2; ks++)
        qf[ks] = *reinterpret_cast<const bf16x8*>(
            Qh + (size_t)(q0 + w * 16 + l15) * 64 + ks * 32 + quad * 8);

    f32x4 o[4];
#pragma unroll
    for (int t = 0; t < 4; t++) o[t] = (f32x4){0.f, 0.f, 0.f, 0.f};
    float rsum[4] = {0.f, 0.f, 0.f, 0.f};

    // swizzled chunk columns for frag reads (row&7 == l15&7 for 16-row tiles)
    const int c0 = (((quad + 0) ^ (l15 & 7)) & 7) * 8;   // ks=0
    const int c1 = (((quad + 4) ^ (l15 & 7)) & 7) * 8;   // ks=1

    // prologue: stage tile 0 into buffer 0 (each wave: 8 rows of K, 8 of V^T)
    gload_lds16(Kh  + (size_t)(w * 8 + drow) * 64 + dcol,   &Ks[0][w * 8][0]);
    gload_lds16(Vth + (size_t)(w * 8 + drow) * 2048 + dcol, &Vs[0][w * 8][0]);
    __syncthreads();

    int cur = 0;
    for (int kt = 0; kt < 32; kt++) {
        // issue next tile's DMA into the other buffer; it drains at the
        // end-of-iteration barrier, i.e. after a full compute phase.
        if (kt < 31) {
            const int kn = kt + 1;
            gload_lds16(Kh  + (size_t)kn * 4096 + (size_t)(w * 8 + drow) * 64 + dcol,
                        &Ks[cur ^ 1][w * 8][0]);
            gload_lds16(Vth + (size_t)(w * 8 + drow) * 2048 + kn * 64 + dcol,
                        &Vs[cur ^ 1][w * 8][0]);
        }

        const unsigned short (*Kc)[64] = Ks[cur];
        const unsigned short (*Vc)[64] = Vs[cur];

        // S = Q~ K^T (scale+ln2 folded into Q); P = exp2(S)
#pragma unroll
        for (int t = 0; t < 4; t++) {
            f32x4 sc = (f32x4){0.f, 0.f, 0.f, 0.f};
            {
                bf16x8 kf = *reinterpret_cast<const bf16x8*>(&Kc[t * 16 + l15][c0]);
                sc = MFMA16(qf[0], kf, sc);
            }
            {
                bf16x8 kf = *reinterpret_cast<const bf16x8*>(&Kc[t * 16 + l15][c1]);
                sc = MFMA16(qf[1], kf, sc);
            }
#pragma unroll
            for (int r = 0; r < 4; r++) {
                const float p = EXP2(sc[r]);
                rsum[r] += p;
                Ps[w][quad * 4 + r][t * 16 + l15] = f2bf(p);
            }
        }

        // hard W->R order on wave-private Ps: drain LDS writes, forbid the
        // scheduler from hoisting the pf reads above this point.
        asm volatile("s_waitcnt lgkmcnt(0)" ::: "memory");
        __builtin_amdgcn_sched_barrier(0);

        bf16x8 pf[2];
#pragma unroll
        for (int ks = 0; ks < 2; ks++)
            pf[ks] = *reinterpret_cast<const bf16x8*>(&Ps[w][l15][ks * 32 + quad * 8]);

#pragma unroll
        for (int t = 0; t < 4; t++) {
            {
                bf16x8 vf = *reinterpret_cast<const bf16x8*>(&Vc[t * 16 + l15][c0]);
                o[t] = MFMA16(pf[0], vf, o[t]);
            }
            {
                bf16x8 vf = *reinterpret_cast<const bf16x8*>(&Vc[t * 16 + l15][c1]);
                o[t] = MFMA16(pf[1], vf, o[t]);
            }
        }

        __syncthreads();   // drains next tile's DMA + guards buffer reuse
        cur ^= 1;
    }

    // deferred l reduction: row quad*4+r spread over 16 lanes sharing quad
#pragma unroll
    for (int off = 1; off < 16; off <<= 1)
#pragma unroll
        for (int r = 0; r < 4; r++)
            rsum[r] += __shfl_xor(rsum[r], off, 64);

    // epilogue: out[b][q][h*64+d], fp32
#pragma unroll
    for (int t = 0; t < 4; t++) {
#pragma unroll
        for (int r = 0; r < 4; r++) {
            const int q = q0 + w * 16 + quad * 4 + r;
            const size_t oidx = (((size_t)b * 2048 + q) * 16 + h) * 64 + t * 16 + l15;
            out[oidx] = o[t][r] / rsum[r];
        }
    }
}

// ---------------------------------------------------------------------------
__global__ void fill_sentinel(float* out, int n, float pat) {
    int i = blockIdx.x * blockDim.x + threadIdx.x;
    if (i < n) out[i] = pat;
}

// ---------------------------------------------------------------------------
extern "C" void kernel_launch(void* const* d_in, const int* in_sizes, int n_in,
                              void* d_out, int out_size, void* d_ws, size_t ws_size,
                              hipStream_t stream) {
    const size_t n_hs  = (size_t)4096 * 1024;
    const size_t n_w   = (size_t)1024 * 1024;
    const size_t n_qkv = n_hs;
    const size_t need = (n_hs + 3 * n_w + 3 * n_qkv) * sizeof(unsigned short);

    bool order_ok = (n_in == 7) &&
        in_sizes[0] == 4194304 &&
        in_sizes[1] == 1048576 && in_sizes[2] == 1024 &&
        in_sizes[3] == 1048576 && in_sizes[4] == 1024 &&
        in_sizes[5] == 1048576 && in_sizes[6] == 1024;
    if (!order_ok || out_size != 4194304) {
        fill_sentinel<<<(out_size + 255) / 256, 256, 0, stream>>>(
            (float*)d_out, out_size, 4.0f);
        return;
    }
    if (ws_size < need) {
        fill_sentinel<<<(out_size + 255) / 256, 256, 0, stream>>>(
            (float*)d_out, out_size, 2.0f);
        return;
    }

    const float* hs = (const float*)d_in[0];
    const float* Wq = (const float*)d_in[1];
    const float* bq = (const float*)d_in[2];
    const float* Wk = (const float*)d_in[3];
    const float* bk = (const float*)d_in[4];
    const float* Wv = (const float*)d_in[5];
    const float* bv = (const float*)d_in[6];

    unsigned short* hsb = (unsigned short*)d_ws;
    unsigned short* Wt  = hsb + n_hs;
    unsigned short* Q   = Wt + 3 * n_w;
    unsigned short* K   = Q + n_qkv;
    unsigned short* Vt  = K + n_qkv;

    cast_hs<<<2048, 256, 0, stream>>>(hs, hsb);
    transpose_cast_w<<<dim3(16, 16, 3), 256, 0, stream>>>(Wq, Wk, Wv, Wt);

    dim3 g1(8, 32, 3);    // (N/128, M/128, {q,k,v})
    qkv_gemm_dma<<<g1, dim3(256), 0, stream>>>(hsb, Wt, bq, bk, bv, Q, K, Vt);

    dim3 g2(16, 16, 2);   // (S/128, H, B)
    attn3<<<g2, dim3(512), 0, stream>>>(Q, K, Vt, (float*)d_out);
}

// Round 3
// 196.844 us; speedup vs baseline: 1.0002x; 1.0002x over previous
//
#include <hip/hip_runtime.h>
#include <hip/hip_bf16.h>

// Problem: B=2, S=2048, D=1024, H=16, dh=64. Inputs fp32, output FP32.
// Round 15 (R14 = 196.9 us, attn3 72.5 us, MfmaUtil 18.4%, FETCH 69.7MB,
// bank-conflicts 6.3e6):
//  - attn3 XCD-bijective block swizzle: flat grid 512; lin%8 selects XCD =
//    bh%8, so all 16 q-blocks of a (b,h) share one XCD -> K/V (512KB/bh,
//    2MB/XCD) L2-resident; prefetch becomes ~200cy L2 hit, hidden under the
//    ~600cy compute phase (was ~900cy HBM miss > phase -> drain stall).
//  - Ps stride 66 -> 68 shorts (34 dwords = 2 mod 32): per-tile u16 stores
//    now hit all 32 banks at 2 lanes/bank (free) vs 4-way quad overlap.
//  - QKV GEMM BK=32 -> 64 (m97-proven structure): halves barrier pairs per
//    K-step; staging 4x 1KB DMA calls per wave per operand.
// R14 carried: pipelined dbuf k-loop, 128 q-rows/8 waves, lgkmcnt+sched
// fence on Ps (correctness-critical), scalar f2bf (m240: cvt_pk asm slower).

typedef __attribute__((ext_vector_type(8))) short bf16x8;
typedef __attribute__((ext_vector_type(4))) float f32x4;
typedef __attribute__((ext_vector_type(4))) int int4v;

#define MFMA16(A, B, C) __builtin_amdgcn_mfma_f32_16x16x32_bf16((A), (B), (C), 0, 0, 0)

#if __has_builtin(__builtin_amdgcn_exp2f)
#define EXP2(x) __builtin_amdgcn_exp2f(x)
#else
#define EXP2(x) exp2f(x)
#endif

static __device__ __forceinline__ unsigned short f2bf(float f) {
    union { float f; unsigned int u; } v;
    v.f = f;
    unsigned int u = v.u;
    u += ((u >> 16) & 1u) + 0x7FFFu;   // RNE
    return (unsigned short)(u >> 16);
}

// async global->LDS DMA, 16B per lane; LDS dest = uniform base + lane*16
static __device__ __forceinline__ void gload_lds16(const void* g, void* l) {
    __builtin_amdgcn_global_load_lds(
        (const __attribute__((address_space(1))) void*)g,
        (__attribute__((address_space(3))) void*)l, 16, 0, 0);
}

// ---------------------------------------------------------------------------
// Pre-pass 1: cast hs fp32 -> bf16. 8 elems/thread.
// ---------------------------------------------------------------------------
__global__ __launch_bounds__(256) void cast_hs(const float* __restrict__ in,
                                               unsigned short* __restrict__ out) {
    const size_t i = ((size_t)blockIdx.x * 256 + threadIdx.x) * 8;
    float4 a0 = *reinterpret_cast<const float4*>(in + i);
    float4 a1 = *reinterpret_cast<const float4*>(in + i + 4);
    unsigned short t[8];
    t[0] = f2bf(a0.x); t[1] = f2bf(a0.y); t[2] = f2bf(a0.z); t[3] = f2bf(a0.w);
    t[4] = f2bf(a1.x); t[5] = f2bf(a1.y); t[6] = f2bf(a1.z); t[7] = f2bf(a1.w);
    *reinterpret_cast<int4v*>(out + i) = *reinterpret_cast<int4v*>(t);
}

// ---------------------------------------------------------------------------
// Pre-pass 2: W[1024][1024] fp32 -> Wt[n][k] bf16 (3 slices via grid.z).
// ---------------------------------------------------------------------------
__global__ __launch_bounds__(256) void transpose_cast_w(
    const float* __restrict__ W0, const float* __restrict__ W1,
    const float* __restrict__ W2, unsigned short* __restrict__ Wt) {
    __shared__ float Ts[64][65];
    const float* W = (blockIdx.z == 0) ? W0 : (blockIdx.z == 1) ? W1 : W2;
    unsigned short* O = Wt + (size_t)blockIdx.z * 1048576;

    const int t  = threadIdx.x;
    const int k0 = blockIdx.y * 64;
    const int n0 = blockIdx.x * 64;

    {
        const int kr = t >> 2, nc = (t & 3) * 16;
        const float* p = W + (size_t)(k0 + kr) * 1024 + n0 + nc;
        float4 r0 = *reinterpret_cast<const float4*>(p);
        float4 r1 = *reinterpret_cast<const float4*>(p + 4);
        float4 r2 = *reinterpret_cast<const float4*>(p + 8);
        float4 r3 = *reinterpret_cast<const float4*>(p + 12);
        float* d = &Ts[kr][nc];
        d[0]=r0.x; d[1]=r0.y; d[2]=r0.z; d[3]=r0.w;
        d[4]=r1.x; d[5]=r1.y; d[6]=r1.z; d[7]=r1.w;
        d[8]=r2.x; d[9]=r2.y; d[10]=r2.z; d[11]=r2.w;
        d[12]=r3.x; d[13]=r3.y; d[14]=r3.z; d[15]=r3.w;
    }
    __syncthreads();
    {
        const int nr = t >> 2, kc = (t & 3) * 16;
        unsigned short tmp[16];
#pragma unroll
        for (int i = 0; i < 16; i++) tmp[i] = f2bf(Ts[kc + i][nr]);
        unsigned short* d = O + (size_t)(n0 + nr) * 1024 + k0 + kc;
        *reinterpret_cast<int4v*>(d)     = *reinterpret_cast<int4v*>(&tmp[0]);
        *reinterpret_cast<int4v*>(d + 8) = *reinterpret_cast<int4v*>(&tmp[8]);
    }
}

// ---------------------------------------------------------------------------
// Kernel 3: QKV GEMM (m97 pattern, DMA staging, 128x128, BK=64).
// Epilogues: z=0 Q natural layout, PRE-SCALED by 0.125*log2(e);
//            z=1 K swizzled cols (d-chunk ^ (s&7));
//            z=2 V^T [B,H,dh,S] swizzled cols (s-chunk ^ (d&7)).
// ---------------------------------------------------------------------------
__global__ __launch_bounds__(256) void qkv_gemm_dma(
    const unsigned short* __restrict__ hsb,
    const unsigned short* __restrict__ Wt,
    const float* __restrict__ b0, const float* __restrict__ b1,
    const float* __restrict__ b2,
    unsigned short* __restrict__ Qo,
    unsigned short* __restrict__ Ko,
    unsigned short* __restrict__ Vto)
{
    __shared__ unsigned short As[128][64];
    __shared__ unsigned short Bs[128][64];

    const int z = blockIdx.z;
    const unsigned short* W = Wt + (size_t)z * 1048576;
    const float* bias = (z == 0) ? b0 : (z == 1) ? b1 : b2;

    const int tid  = threadIdx.x;
    const int lane = tid & 63;
    const int w    = tid >> 6;
    const int l15  = lane & 15;
    const int quad = lane >> 4;
    const int m0   = blockIdx.y * 128;
    const int n0   = blockIdx.x * 128;
    const int wm   = (w >> 1) * 64;
    const int wn   = (w & 1) * 64;

    const int drow = lane >> 3;        // 0..7
    const int dcol = (lane & 7) * 8;   // 0..56 shorts

    f32x4 acc[4][4];
#pragma unroll
    for (int i = 0; i < 4; i++)
#pragma unroll
        for (int j = 0; j < 4; j++)
            acc[i][j] = (f32x4){0.f, 0.f, 0.f, 0.f};

    for (int k0 = 0; k0 < 1024; k0 += 64) {
        __syncthreads();
#pragma unroll
        for (int p = 0; p < 4; p++) {
            const int s = w * 32 + p * 8;   // wave w stages rows [32w, 32w+32)
            gload_lds16(hsb + (size_t)(m0 + s + drow) * 1024 + k0 + dcol,
                        &As[s][0]);
            gload_lds16(W   + (size_t)(n0 + s + drow) * 1024 + k0 + dcol,
                        &Bs[s][0]);
        }
        __syncthreads();

#pragma unroll
        for (int kk = 0; kk < 2; kk++) {
            bf16x8 af[4], bfr[4];
#pragma unroll
            for (int i = 0; i < 4; i++)
                af[i] = *reinterpret_cast<const bf16x8*>(
                    &As[wm + i * 16 + l15][kk * 32 + quad * 8]);
#pragma unroll
            for (int j = 0; j < 4; j++)
                bfr[j] = *reinterpret_cast<const bf16x8*>(
                    &Bs[wn + j * 16 + l15][kk * 32 + quad * 8]);
#pragma unroll
            for (int i = 0; i < 4; i++)
#pragma unroll
                for (int j = 0; j < 4; j++)
                    acc[i][j] = MFMA16(af[i], bfr[j], acc[i][j]);
        }
    }

    if (z == 0) {
        // Q: natural [B,H,S,dh], pre-scaled by 0.125*log2(e)
        const float qs = 0.18033688f;
#pragma unroll
        for (int i = 0; i < 4; i++) {
            const int mbase = m0 + wm + i * 16 + quad * 4;
#pragma unroll
            for (int j = 0; j < 4; j++) {
                const int n = n0 + wn + j * 16 + l15;
                const int h = n >> 6, d = n & 63;
                const float bn = bias[n];
#pragma unroll
                for (int r = 0; r < 4; r++) {
                    const int mm = mbase + r;
                    const int b = mm >> 11, s = mm & 2047;
                    Qo[(((size_t)(b * 16 + h) * 2048 + s) * 64) + d] =
                        f2bf((acc[i][j][r] + bn) * qs);
                }
            }
        }
    } else if (z == 1) {
        // K: [B,H,S,dh] with d-chunk swizzle by (s&7)
#pragma unroll
        for (int i = 0; i < 4; i++) {
            const int mbase = m0 + wm + i * 16 + quad * 4;
#pragma unroll
            for (int j = 0; j < 4; j++) {
                const int n = n0 + wn + j * 16 + l15;
                const int h = n >> 6, d = n & 63;
                const float bn = bias[n];
#pragma unroll
                for (int r = 0; r < 4; r++) {
                    const int mm = mbase + r;
                    const int b = mm >> 11, s = mm & 2047;
                    const int dsw = ((((d >> 3) ^ (s & 7)) & 7) << 3) | (d & 7);
                    Ko[(((size_t)(b * 16 + h) * 2048 + s) * 64) + dsw] =
                        f2bf(acc[i][j][r] + bn);
                }
            }
        }
    } else {
        // V^T: [B,H,dh,S] with s-chunk swizzle by (d&7); 4 consecutive s packed
#pragma unroll
        for (int i = 0; i < 4; i++) {
            const int mbase = m0 + wm + i * 16 + quad * 4;
            const int b = mbase >> 11, s0 = mbase & 2047;
#pragma unroll
            for (int j = 0; j < 4; j++) {
                const int n = n0 + wn + j * 16 + l15;
                const int h = n >> 6, d = n & 63;
                const float bn = bias[n];
                ushort4 v4;
                v4.x = f2bf(acc[i][j][0] + bn);
                v4.y = f2bf(acc[i][j][1] + bn);
                v4.z = f2bf(acc[i][j][2] + bn);
                v4.w = f2bf(acc[i][j][3] + bn);
                const int cs  = (s0 & 63) >> 3;
                const int ssw = (s0 & ~63) | (((cs ^ (d & 7)) & 7) << 3) | (s0 & 7);
                *reinterpret_cast<ushort4*>(
                    Vto + ((size_t)(b * 16 + h) * 64 + d) * 2048 + ssw) = v4;
            }
        }
    }
}

// ---------------------------------------------------------------------------
// Kernel 4: MFMA flash attention, max-free softmax, swizzled K/V^T tiles.
// 1 block = (b,h,128 q-rows), 8 waves; wave w owns q-rows [16w,16w+16).
// Pipelined: K/V double-buffered, next tile's DMA issued before compute,
// one __syncthreads per tile (its vmcnt drain = prefetch completion).
// Flat grid 512, XCD-bijective: lin%8 = bh%8 -> all 16 q-blocks of a (b,h)
// on one XCD; its L2 holds K/V for 4 bh (2MB of 4MB).
// ---------------------------------------------------------------------------
__global__ __launch_bounds__(512) void attn3(
    const unsigned short* __restrict__ Qg,
    const unsigned short* __restrict__ Kg,
    const unsigned short* __restrict__ Vtg,
    float* __restrict__ out)
{
    __shared__ unsigned short Ks[2][64][64];   // [buf][kk][d] swizzled (DMA)
    __shared__ unsigned short Vs[2][64][64];   // [buf] V^T tile [d][kk] swizzled (DMA)
    __shared__ unsigned short Ps[8][16][68];   // per-wave P [qrow][kk], stride 68
                                               // (34 dw = 2 mod 32: stores spread
                                               //  all 32 banks, 2 lanes/bank)

    const int tid  = threadIdx.x;
    const int lane = tid & 63;
    const int w    = tid >> 6;        // 0..7
    const int l15  = lane & 15;
    const int quad = lane >> 4;

    // XCD-bijective decode: lin = (bh&7) + 8*qb + 128*(bh>>3)
    const int lin = blockIdx.x;               // 0..511
    const int qb  = (lin >> 3) & 15;
    const int bh  = (lin & 7) | ((lin >> 7) << 3);
    const int q0  = qb * 128;
    const size_t base = (size_t)bh * 2048 * 64;
    const unsigned short* Qh  = Qg  + base;
    const unsigned short* Kh  = Kg  + base;
    const unsigned short* Vth = Vtg + base;
    const int b = bh >> 4;
    const int h = bh & 15;

    const int drow = lane >> 3;       // 0..7
    const int dcol = (lane & 7) * 8;  // 0..56

    bf16x8 qf[2];
#pragma unroll
    for (int ks = 0; ks < 2; ks++)
        qf[ks] = *reinterpret_cast<const bf16x8*>(
            Qh + (size_t)(q0 + w * 16 + l15) * 64 + ks * 32 + quad * 8);

    f32x4 o[4];
#pragma unroll
    for (int t = 0; t < 4; t++) o[t] = (f32x4){0.f, 0.f, 0.f, 0.f};
    float rsum[4] = {0.f, 0.f, 0.f, 0.f};

    // swizzled chunk columns for frag reads (row&7 == l15&7 for 16-row tiles)
    const int c0 = (((quad + 0) ^ (l15 & 7)) & 7) * 8;   // ks=0
    const int c1 = (((quad + 4) ^ (l15 & 7)) & 7) * 8;   // ks=1

    // prologue: stage tile 0 into buffer 0 (each wave: 8 rows of K, 8 of V^T)
    gload_lds16(Kh  + (size_t)(w * 8 + drow) * 64 + dcol,   &Ks[0][w * 8][0]);
    gload_lds16(Vth + (size_t)(w * 8 + drow) * 2048 + dcol, &Vs[0][w * 8][0]);
    __syncthreads();

    int cur = 0;
    for (int kt = 0; kt < 32; kt++) {
        // issue next tile's DMA into the other buffer; it drains at the
        // end-of-iteration barrier, i.e. after a full compute phase.
        if (kt < 31) {
            const int kn = kt + 1;
            gload_lds16(Kh  + (size_t)kn * 4096 + (size_t)(w * 8 + drow) * 64 + dcol,
                        &Ks[cur ^ 1][w * 8][0]);
            gload_lds16(Vth + (size_t)(w * 8 + drow) * 2048 + kn * 64 + dcol,
                        &Vs[cur ^ 1][w * 8][0]);
        }

        const unsigned short (*Kc)[64] = Ks[cur];
        const unsigned short (*Vc)[64] = Vs[cur];

        // S = Q~ K^T (scale+ln2 folded into Q); P = exp2(S)
#pragma unroll
        for (int t = 0; t < 4; t++) {
            f32x4 sc = (f32x4){0.f, 0.f, 0.f, 0.f};
            {
                bf16x8 kf = *reinterpret_cast<const bf16x8*>(&Kc[t * 16 + l15][c0]);
                sc = MFMA16(qf[0], kf, sc);
            }
            {
                bf16x8 kf = *reinterpret_cast<const bf16x8*>(&Kc[t * 16 + l15][c1]);
                sc = MFMA16(qf[1], kf, sc);
            }
#pragma unroll
            for (int r = 0; r < 4; r++) {
                const float p = EXP2(sc[r]);
                rsum[r] += p;
                Ps[w][quad * 4 + r][t * 16 + l15] = f2bf(p);
            }
        }

        // hard W->R order on wave-private Ps: drain LDS writes, forbid the
        // scheduler from hoisting the pf reads above this point.
        asm volatile("s_waitcnt lgkmcnt(0)" ::: "memory");
        __builtin_amdgcn_sched_barrier(0);

        bf16x8 pf[2];
#pragma unroll
        for (int ks = 0; ks < 2; ks++)
            pf[ks] = *reinterpret_cast<const bf16x8*>(&Ps[w][l15][ks * 32 + quad * 8]);

#pragma unroll
        for (int t = 0; t < 4; t++) {
            {
                bf16x8 vf = *reinterpret_cast<const bf16x8*>(&Vc[t * 16 + l15][c0]);
                o[t] = MFMA16(pf[0], vf, o[t]);
            }
            {
                bf16x8 vf = *reinterpret_cast<const bf16x8*>(&Vc[t * 16 + l15][c1]);
                o[t] = MFMA16(pf[1], vf, o[t]);
            }
        }

        __syncthreads();   // drains next tile's DMA + guards buffer reuse
        cur ^= 1;
    }

    // deferred l reduction: row quad*4+r spread over 16 lanes sharing quad
#pragma unroll
    for (int off = 1; off < 16; off <<= 1)
#pragma unroll
        for (int r = 0; r < 4; r++)
            rsum[r] += __shfl_xor(rsum[r], off, 64);

    // epilogue: out[b][q][h*64+d], fp32
#pragma unroll
    for (int t = 0; t < 4; t++) {
#pragma unroll
        for (int r = 0; r < 4; r++) {
            const int q = q0 + w * 16 + quad * 4 + r;
            const size_t oidx = (((size_t)b * 2048 + q) * 16 + h) * 64 + t * 16 + l15;
            out[oidx] = o[t][r] / rsum[r];
        }
    }
}

// ---------------------------------------------------------------------------
__global__ void fill_sentinel(float* out, int n, float pat) {
    int i = blockIdx.x * blockDim.x + threadIdx.x;
    if (i < n) out[i] = pat;
}

// ---------------------------------------------------------------------------
extern "C" void kernel_launch(void* const* d_in, const int* in_sizes, int n_in,
                              void* d_out, int out_size, void* d_ws, size_t ws_size,
                              hipStream_t stream) {
    const size_t n_hs  = (size_t)4096 * 1024;
    const size_t n_w   = (size_t)1024 * 1024;
    const size_t n_qkv = n_hs;
    const size_t need = (n_hs + 3 * n_w + 3 * n_qkv) * sizeof(unsigned short);

    bool order_ok = (n_in == 7) &&
        in_sizes[0] == 4194304 &&
        in_sizes[1] == 1048576 && in_sizes[2] == 1024 &&
        in_sizes[3] == 1048576 && in_sizes[4] == 1024 &&
        in_sizes[5] == 1048576 && in_sizes[6] == 1024;
    if (!order_ok || out_size != 4194304) {
        fill_sentinel<<<(out_size + 255) / 256, 256, 0, stream>>>(
            (float*)d_out, out_size, 4.0f);
        return;
    }
    if (ws_size < need) {
        fill_sentinel<<<(out_size + 255) / 256, 256, 0, stream>>>(
            (float*)d_out, out_size, 2.0f);
        return;
    }

    const float* hs = (const float*)d_in[0];
    const float* Wq = (const float*)d_in[1];
    const float* bq = (const float*)d_in[2];
    const float* Wk = (const float*)d_in[3];
    const float* bk = (const float*)d_in[4];
    const float* Wv = (const float*)d_in[5];
    const float* bv = (const float*)d_in[6];

    unsigned short* hsb = (unsigned short*)d_ws;
    unsigned short* Wt  = hsb + n_hs;
    unsigned short* Q   = Wt + 3 * n_w;
    unsigned short* K   = Q + n_qkv;
    unsigned short* Vt  = K + n_qkv;

    cast_hs<<<2048, 256, 0, stream>>>(hs, hsb);
    transpose_cast_w<<<dim3(16, 16, 3), 256, 0, stream>>>(Wq, Wk, Wv, Wt);

    dim3 g1(8, 32, 3);    // (N/128, M/128, {q,k,v})
    qkv_gemm_dma<<<g1, dim3(256), 0, stream>>>(hsb, Wt, bq, bk, bv, Q, K, Vt);

    attn3<<<dim3(512), dim3(512), 0, stream>>>(Q, K, Vt, (float*)d_out);
}

// Round 4
// 193.619 us; speedup vs baseline: 1.0169x; 1.0167x over previous
//
#include <hip/hip_runtime.h>
#include <hip/hip_bf16.h>

// Problem: B=2, S=2048, D=1024, H=16, dh=64. Inputs fp32, output FP32.
// Round 16 (R15 = 196.8 us; attn3 65.8 us, MfmaUtil 20.5%, conflicts 0,
// FETCH 12.3MB -- XCD swizzle + stride-68 both verified; GEMM BK=64
// regressed +6.6 us, exactly offsetting the attn win).
//  - GEMM reverted to R14's proven BK=32 (m132 lesson: bigger K-tile loses
//    in the 2-barrier structure).
//  - attn3 is LDS-throughput-bound (per-CU LDS cycle model: 2 blk x 8 waves
//    x 32 tiles x ~296cy = 63 us ~= measured 65.8). Restructured to 4 waves
//    x 32 q-rows (same 128 q/block): K/V frag reads are per-wave, so each
//    b128 read now feeds 2x MFMAs -> per-CU LDS traffic -32%. Same LDS
//    total (50176B), same Ps stride 68 (0-conflict), same fence idiom,
//    same XCD-bijective flat grid 512.
// Carried: pipelined dbuf k-loop, lgkmcnt+sched_barrier fence on Ps
// (correctness-critical), scalar f2bf (m240), max-free softmax.

typedef __attribute__((ext_vector_type(8))) short bf16x8;
typedef __attribute__((ext_vector_type(4))) float f32x4;
typedef __attribute__((ext_vector_type(4))) int int4v;

#define MFMA16(A, B, C) __builtin_amdgcn_mfma_f32_16x16x32_bf16((A), (B), (C), 0, 0, 0)

#if __has_builtin(__builtin_amdgcn_exp2f)
#define EXP2(x) __builtin_amdgcn_exp2f(x)
#else
#define EXP2(x) exp2f(x)
#endif

static __device__ __forceinline__ unsigned short f2bf(float f) {
    union { float f; unsigned int u; } v;
    v.f = f;
    unsigned int u = v.u;
    u += ((u >> 16) & 1u) + 0x7FFFu;   // RNE
    return (unsigned short)(u >> 16);
}

// async global->LDS DMA, 16B per lane; LDS dest = uniform base + lane*16
static __device__ __forceinline__ void gload_lds16(const void* g, void* l) {
    __builtin_amdgcn_global_load_lds(
        (const __attribute__((address_space(1))) void*)g,
        (__attribute__((address_space(3))) void*)l, 16, 0, 0);
}

// ---------------------------------------------------------------------------
// Pre-pass 1: cast hs fp32 -> bf16. 8 elems/thread.
// ---------------------------------------------------------------------------
__global__ __launch_bounds__(256) void cast_hs(const float* __restrict__ in,
                                               unsigned short* __restrict__ out) {
    const size_t i = ((size_t)blockIdx.x * 256 + threadIdx.x) * 8;
    float4 a0 = *reinterpret_cast<const float4*>(in + i);
    float4 a1 = *reinterpret_cast<const float4*>(in + i + 4);
    unsigned short t[8];
    t[0] = f2bf(a0.x); t[1] = f2bf(a0.y); t[2] = f2bf(a0.z); t[3] = f2bf(a0.w);
    t[4] = f2bf(a1.x); t[5] = f2bf(a1.y); t[6] = f2bf(a1.z); t[7] = f2bf(a1.w);
    *reinterpret_cast<int4v*>(out + i) = *reinterpret_cast<int4v*>(t);
}

// ---------------------------------------------------------------------------
// Pre-pass 2: W[1024][1024] fp32 -> Wt[n][k] bf16 (3 slices via grid.z).
// ---------------------------------------------------------------------------
__global__ __launch_bounds__(256) void transpose_cast_w(
    const float* __restrict__ W0, const float* __restrict__ W1,
    const float* __restrict__ W2, unsigned short* __restrict__ Wt) {
    __shared__ float Ts[64][65];
    const float* W = (blockIdx.z == 0) ? W0 : (blockIdx.z == 1) ? W1 : W2;
    unsigned short* O = Wt + (size_t)blockIdx.z * 1048576;

    const int t  = threadIdx.x;
    const int k0 = blockIdx.y * 64;
    const int n0 = blockIdx.x * 64;

    {
        const int kr = t >> 2, nc = (t & 3) * 16;
        const float* p = W + (size_t)(k0 + kr) * 1024 + n0 + nc;
        float4 r0 = *reinterpret_cast<const float4*>(p);
        float4 r1 = *reinterpret_cast<const float4*>(p + 4);
        float4 r2 = *reinterpret_cast<const float4*>(p + 8);
        float4 r3 = *reinterpret_cast<const float4*>(p + 12);
        float* d = &Ts[kr][nc];
        d[0]=r0.x; d[1]=r0.y; d[2]=r0.z; d[3]=r0.w;
        d[4]=r1.x; d[5]=r1.y; d[6]=r1.z; d[7]=r1.w;
        d[8]=r2.x; d[9]=r2.y; d[10]=r2.z; d[11]=r2.w;
        d[12]=r3.x; d[13]=r3.y; d[14]=r3.z; d[15]=r3.w;
    }
    __syncthreads();
    {
        const int nr = t >> 2, kc = (t & 3) * 16;
        unsigned short tmp[16];
#pragma unroll
        for (int i = 0; i < 16; i++) tmp[i] = f2bf(Ts[kc + i][nr]);
        unsigned short* d = O + (size_t)(n0 + nr) * 1024 + k0 + kc;
        *reinterpret_cast<int4v*>(d)     = *reinterpret_cast<int4v*>(&tmp[0]);
        *reinterpret_cast<int4v*>(d + 8) = *reinterpret_cast<int4v*>(&tmp[8]);
    }
}

// ---------------------------------------------------------------------------
// Kernel 3: QKV GEMM (m97 pattern, DMA staging, 128x128, BK=32 -- R14 proven).
// Epilogues: z=0 Q natural layout, PRE-SCALED by 0.125*log2(e);
//            z=1 K swizzled cols (d-chunk ^ (s&7));
//            z=2 V^T [B,H,dh,S] swizzled cols (s-chunk ^ (d&7)).
// ---------------------------------------------------------------------------
__global__ __launch_bounds__(256) void qkv_gemm_dma(
    const unsigned short* __restrict__ hsb,
    const unsigned short* __restrict__ Wt,
    const float* __restrict__ b0, const float* __restrict__ b1,
    const float* __restrict__ b2,
    unsigned short* __restrict__ Qo,
    unsigned short* __restrict__ Ko,
    unsigned short* __restrict__ Vto)
{
    __shared__ unsigned short As[128][32];
    __shared__ unsigned short Bs[128][32];

    const int z = blockIdx.z;
    const unsigned short* W = Wt + (size_t)z * 1048576;
    const float* bias = (z == 0) ? b0 : (z == 1) ? b1 : b2;

    const int tid  = threadIdx.x;
    const int lane = tid & 63;
    const int w    = tid >> 6;
    const int l15  = lane & 15;
    const int quad = lane >> 4;
    const int m0   = blockIdx.y * 128;
    const int n0   = blockIdx.x * 128;
    const int wm   = (w >> 1) * 64;
    const int wn   = (w & 1) * 64;

    const int drow = lane >> 2;
    const int dcol = (lane & 3) * 8;

    f32x4 acc[4][4];
#pragma unroll
    for (int i = 0; i < 4; i++)
#pragma unroll
        for (int j = 0; j < 4; j++)
            acc[i][j] = (f32x4){0.f, 0.f, 0.f, 0.f};

    for (int k0 = 0; k0 < 1024; k0 += 32) {
        __syncthreads();
#pragma unroll
        for (int p = 0; p < 2; p++) {
            const int s = w * 2 + p;
            gload_lds16(hsb + (size_t)(m0 + s * 16 + drow) * 1024 + k0 + dcol,
                        &As[s * 16][0]);
            gload_lds16(W   + (size_t)(n0 + s * 16 + drow) * 1024 + k0 + dcol,
                        &Bs[s * 16][0]);
        }
        __syncthreads();

        bf16x8 af[4], bfr[4];
#pragma unroll
        for (int i = 0; i < 4; i++)
            af[i] = *reinterpret_cast<const bf16x8*>(&As[wm + i * 16 + l15][quad * 8]);
#pragma unroll
        for (int j = 0; j < 4; j++)
            bfr[j] = *reinterpret_cast<const bf16x8*>(&Bs[wn + j * 16 + l15][quad * 8]);
#pragma unroll
        for (int i = 0; i < 4; i++)
#pragma unroll
            for (int j = 0; j < 4; j++)
                acc[i][j] = MFMA16(af[i], bfr[j], acc[i][j]);
    }

    if (z == 0) {
        // Q: natural [B,H,S,dh], pre-scaled by 0.125*log2(e)
        const float qs = 0.18033688f;
#pragma unroll
        for (int i = 0; i < 4; i++) {
            const int mbase = m0 + wm + i * 16 + quad * 4;
#pragma unroll
            for (int j = 0; j < 4; j++) {
                const int n = n0 + wn + j * 16 + l15;
                const int h = n >> 6, d = n & 63;
                const float bn = bias[n];
#pragma unroll
                for (int r = 0; r < 4; r++) {
                    const int mm = mbase + r;
                    const int b = mm >> 11, s = mm & 2047;
                    Qo[(((size_t)(b * 16 + h) * 2048 + s) * 64) + d] =
                        f2bf((acc[i][j][r] + bn) * qs);
                }
            }
        }
    } else if (z == 1) {
        // K: [B,H,S,dh] with d-chunk swizzle by (s&7)
#pragma unroll
        for (int i = 0; i < 4; i++) {
            const int mbase = m0 + wm + i * 16 + quad * 4;
#pragma unroll
            for (int j = 0; j < 4; j++) {
                const int n = n0 + wn + j * 16 + l15;
                const int h = n >> 6, d = n & 63;
                const float bn = bias[n];
#pragma unroll
                for (int r = 0; r < 4; r++) {
                    const int mm = mbase + r;
                    const int b = mm >> 11, s = mm & 2047;
                    const int dsw = ((((d >> 3) ^ (s & 7)) & 7) << 3) | (d & 7);
                    Ko[(((size_t)(b * 16 + h) * 2048 + s) * 64) + dsw] =
                        f2bf(acc[i][j][r] + bn);
                }
            }
        }
    } else {
        // V^T: [B,H,dh,S] with s-chunk swizzle by (d&7); 4 consecutive s packed
#pragma unroll
        for (int i = 0; i < 4; i++) {
            const int mbase = m0 + wm + i * 16 + quad * 4;
            const int b = mbase >> 11, s0 = mbase & 2047;
#pragma unroll
            for (int j = 0; j < 4; j++) {
                const int n = n0 + wn + j * 16 + l15;
                const int h = n >> 6, d = n & 63;
                const float bn = bias[n];
                ushort4 v4;
                v4.x = f2bf(acc[i][j][0] + bn);
                v4.y = f2bf(acc[i][j][1] + bn);
                v4.z = f2bf(acc[i][j][2] + bn);
                v4.w = f2bf(acc[i][j][3] + bn);
                const int cs  = (s0 & 63) >> 3;
                const int ssw = (s0 & ~63) | (((cs ^ (d & 7)) & 7) << 3) | (s0 & 7);
                *reinterpret_cast<ushort4*>(
                    Vto + ((size_t)(b * 16 + h) * 64 + d) * 2048 + ssw) = v4;
            }
        }
    }
}

// ---------------------------------------------------------------------------
// Kernel 4: MFMA flash attention, max-free softmax, swizzled K/V^T tiles.
// 1 block = (b,h,128 q-rows), 4 waves; wave w owns q-rows [32w,32w+32) as
// two 16-row groups g. K/V frag reads per wave are amortized over 2x MFMAs
// vs the 8-wave/16-q layout (LDS-throughput-bound fix).
// Pipelined: K/V double-buffered, next tile's DMA issued before compute,
// one __syncthreads per tile (its vmcnt drain = prefetch completion).
// Flat grid 512, XCD-bijective: lin%8 = bh%8 -> all 16 q-blocks of a (b,h)
// on one XCD; its L2 holds K/V for 4 bh (2MB of 4MB).
// ---------------------------------------------------------------------------
__global__ __launch_bounds__(256) void attn3(
    const unsigned short* __restrict__ Qg,
    const unsigned short* __restrict__ Kg,
    const unsigned short* __restrict__ Vtg,
    float* __restrict__ out)
{
    __shared__ unsigned short Ks[2][64][64];   // [buf][kk][d] swizzled (DMA)
    __shared__ unsigned short Vs[2][64][64];   // [buf] V^T tile [d][kk] swizzled (DMA)
    __shared__ unsigned short Ps[4][32][68];   // per-wave P [qrow][kk], stride 68
                                               // (34 dw = 2 mod 32: 0 conflicts,
                                               //  measured R15)

    const int tid  = threadIdx.x;
    const int lane = tid & 63;
    const int w    = tid >> 6;        // 0..3
    const int l15  = lane & 15;
    const int quad = lane >> 4;

    // XCD-bijective decode: lin = (bh&7) + 8*qb + 128*(bh>>3)
    const int lin = blockIdx.x;               // 0..511
    const int qb  = (lin >> 3) & 15;
    const int bh  = (lin & 7) | ((lin >> 7) << 3);
    const int q0  = qb * 128;
    const size_t base = (size_t)bh * 2048 * 64;
    const unsigned short* Qh  = Qg  + base;
    const unsigned short* Kh  = Kg  + base;
    const unsigned short* Vth = Vtg + base;
    const int b = bh >> 4;
    const int h = bh & 15;

    const int drow = lane >> 3;       // 0..7
    const int dcol = (lane & 7) * 8;  // 0..56

    bf16x8 qf[2][2];
#pragma unroll
    for (int g = 0; g < 2; g++)
#pragma unroll
        for (int ks = 0; ks < 2; ks++)
            qf[g][ks] = *reinterpret_cast<const bf16x8*>(
                Qh + (size_t)(q0 + w * 32 + g * 16 + l15) * 64 + ks * 32 + quad * 8);

    f32x4 o[2][4];
#pragma unroll
    for (int g = 0; g < 2; g++)
#pragma unroll
        for (int t = 0; t < 4; t++) o[g][t] = (f32x4){0.f, 0.f, 0.f, 0.f};
    float rsum[2][4] = {{0.f, 0.f, 0.f, 0.f}, {0.f, 0.f, 0.f, 0.f}};

    // swizzled chunk columns for frag reads (row&7 == l15&7 for 16-row tiles)
    const int c0 = (((quad + 0) ^ (l15 & 7)) & 7) * 8;   // ks=0
    const int c1 = (((quad + 4) ^ (l15 & 7)) & 7) * 8;   // ks=1

    // prologue: stage tile 0 into buffer 0 (each wave: 16 rows of K, 16 of V^T)
#pragma unroll
    for (int p = 0; p < 2; p++) {
        const int s = w * 16 + p * 8;
        gload_lds16(Kh  + (size_t)(s + drow) * 64 + dcol,   &Ks[0][s][0]);
        gload_lds16(Vth + (size_t)(s + drow) * 2048 + dcol, &Vs[0][s][0]);
    }
    __syncthreads();

    int cur = 0;
    for (int kt = 0; kt < 32; kt++) {
        // issue next tile's DMA into the other buffer; it drains at the
        // end-of-iteration barrier, i.e. after a full compute phase.
        if (kt < 31) {
            const int kn = kt + 1;
#pragma unroll
            for (int p = 0; p < 2; p++) {
                const int s = w * 16 + p * 8;
                gload_lds16(Kh  + (size_t)kn * 4096 + (size_t)(s + drow) * 64 + dcol,
                            &Ks[cur ^ 1][s][0]);
                gload_lds16(Vth + (size_t)(s + drow) * 2048 + kn * 64 + dcol,
                            &Vs[cur ^ 1][s][0]);
            }
        }

        const unsigned short (*Kc)[64] = Ks[cur];
        const unsigned short (*Vc)[64] = Vs[cur];

        // S = Q~ K^T (scale+ln2 folded into Q); P = exp2(S).
        // kf reads shared by both 16-row q-groups.
#pragma unroll
        for (int t = 0; t < 4; t++) {
            bf16x8 kf0 = *reinterpret_cast<const bf16x8*>(&Kc[t * 16 + l15][c0]);
            bf16x8 kf1 = *reinterpret_cast<const bf16x8*>(&Kc[t * 16 + l15][c1]);
#pragma unroll
            for (int g = 0; g < 2; g++) {
                f32x4 sc = (f32x4){0.f, 0.f, 0.f, 0.f};
                sc = MFMA16(qf[g][0], kf0, sc);
                sc = MFMA16(qf[g][1], kf1, sc);
#pragma unroll
                for (int r = 0; r < 4; r++) {
                    const float p = EXP2(sc[r]);
                    rsum[g][r] += p;
                    Ps[w][g * 16 + quad * 4 + r][t * 16 + l15] = f2bf(p);
                }
            }
        }

        // hard W->R order on wave-private Ps: drain LDS writes, forbid the
        // scheduler from hoisting the pf reads above this point.
        asm volatile("s_waitcnt lgkmcnt(0)" ::: "memory");
        __builtin_amdgcn_sched_barrier(0);

        bf16x8 pf[2][2];
#pragma unroll
        for (int g = 0; g < 2; g++)
#pragma unroll
            for (int ks = 0; ks < 2; ks++)
                pf[g][ks] = *reinterpret_cast<const bf16x8*>(
                    &Ps[w][g * 16 + l15][ks * 32 + quad * 8]);

        // PV: vf reads shared by both q-groups.
#pragma unroll
        for (int t = 0; t < 4; t++) {
            bf16x8 vf0 = *reinterpret_cast<const bf16x8*>(&Vc[t * 16 + l15][c0]);
            bf16x8 vf1 = *reinterpret_cast<const bf16x8*>(&Vc[t * 16 + l15][c1]);
#pragma unroll
            for (int g = 0; g < 2; g++) {
                o[g][t] = MFMA16(pf[g][0], vf0, o[g][t]);
                o[g][t] = MFMA16(pf[g][1], vf1, o[g][t]);
            }
        }

        __syncthreads();   // drains next tile's DMA + guards buffer reuse
        cur ^= 1;
    }

    // deferred l reduction: row's 16 score-cols live in the 16 lanes sharing quad
#pragma unroll
    for (int off = 1; off < 16; off <<= 1)
#pragma unroll
        for (int g = 0; g < 2; g++)
#pragma unroll
            for (int r = 0; r < 4; r++)
                rsum[g][r] += __shfl_xor(rsum[g][r], off, 64);

    // epilogue: out[b][q][h*64+d], fp32
#pragma unroll
    for (int g = 0; g < 2; g++)
#pragma unroll
        for (int t = 0; t < 4; t++)
#pragma unroll
            for (int r = 0; r < 4; r++) {
                const int q = q0 + w * 32 + g * 16 + quad * 4 + r;
                const size_t oidx =
                    (((size_t)b * 2048 + q) * 16 + h) * 64 + t * 16 + l15;
                out[oidx] = o[g][t][r] / rsum[g][r];
            }
}

// ---------------------------------------------------------------------------
__global__ void fill_sentinel(float* out, int n, float pat) {
    int i = blockIdx.x * blockDim.x + threadIdx.x;
    if (i < n) out[i] = pat;
}

// ---------------------------------------------------------------------------
extern "C" void kernel_launch(void* const* d_in, const int* in_sizes, int n_in,
                              void* d_out, int out_size, void* d_ws, size_t ws_size,
                              hipStream_t stream) {
    const size_t n_hs  = (size_t)4096 * 1024;
    const size_t n_w   = (size_t)1024 * 1024;
    const size_t n_qkv = n_hs;
    const size_t need = (n_hs + 3 * n_w + 3 * n_qkv) * sizeof(unsigned short);

    bool order_ok = (n_in == 7) &&
        in_sizes[0] == 4194304 &&
        in_sizes[1] == 1048576 && in_sizes[2] == 1024 &&
        in_sizes[3] == 1048576 && in_sizes[4] == 1024 &&
        in_sizes[5] == 1048576 && in_sizes[6] == 1024;
    if (!order_ok || out_size != 4194304) {
        fill_sentinel<<<(out_size + 255) / 256, 256, 0, stream>>>(
            (float*)d_out, out_size, 4.0f);
        return;
    }
    if (ws_size < need) {
        fill_sentinel<<<(out_size + 255) / 256, 256, 0, stream>>>(
            (float*)d_out, out_size, 2.0f);
        return;
    }

    const float* hs = (const float*)d_in[0];
    const float* Wq = (const float*)d_in[1];
    const float* bq = (const float*)d_in[2];
    const float* Wk = (const float*)d_in[3];
    const float* bk = (const float*)d_in[4];
    const float* Wv = (const float*)d_in[5];
    const float* bv = (const float*)d_in[6];

    unsigned short* hsb = (unsigned short*)d_ws;
    unsigned short* Wt  = hsb + n_hs;
    unsigned short* Q   = Wt + 3 * n_w;
    unsigned short* K   = Q + n_qkv;
    unsigned short* Vt  = K + n_qkv;

    cast_hs<<<2048, 256, 0, stream>>>(hs, hsb);
    transpose_cast_w<<<dim3(16, 16, 3), 256, 0, stream>>>(Wq, Wk, Wv, Wt);

    dim3 g1(8, 32, 3);    // (N/128, M/128, {q,k,v})
    qkv_gemm_dma<<<g1, dim3(256), 0, stream>>>(hsb, Wt, bq, bk, bv, Q, K, Vt);

    attn3<<<dim3(512), dim3(256), 0, stream>>>(Q, K, Vt, (float*)d_out);
}

// Round 5
// 188.249 us; speedup vs baseline: 1.0459x; 1.0285x over previous
//
#include <hip/hip_runtime.h>
#include <hip/hip_bf16.h>

// Problem: B=2, S=2048, D=1024, H=16, dh=64. Inputs fp32, output FP32.
// Round 17 (R16 = 193.6 us; attn3 REGRESSED 65.8 -> 79.2 us: 4-wave blocks
// halved resident waves (Occupancy 34.6 -> 21%) -- kernel is LATENCY-bound,
// not LDS-throughput-bound; 16 waves/CU is the binding constraint).
//  - attn3 reverted to R15's proven 8-wave/16-q structure (65.8 us measured).
//  - Ps stores via __float2bfloat16 cast (compiler emits packed
//    v_cvt_pk_bf16_f32; m240: scalar CAST is the fast form) -- removes ~80
//    VALU ops/tile from the QK->PV critical chain. RNE, numerics identical.
//  - s_setprio(1/0) around MFMA pairs (T5; m191: +4-7% on multi-wave attn).
// Carried: XCD-bijective flat grid (FETCH 12.3MB), Ps stride 68 (0 bank
// conflicts), pipelined dbuf k-loop, lgkmcnt+sched_barrier fence
// (correctness-critical), BK=32 GEMM (BK=64 regressed, m132).

typedef __attribute__((ext_vector_type(8))) short bf16x8;
typedef __attribute__((ext_vector_type(4))) float f32x4;
typedef __attribute__((ext_vector_type(4))) int int4v;

#define MFMA16(A, B, C) __builtin_amdgcn_mfma_f32_16x16x32_bf16((A), (B), (C), 0, 0, 0)

#if __has_builtin(__builtin_amdgcn_exp2f)
#define EXP2(x) __builtin_amdgcn_exp2f(x)
#else
#define EXP2(x) exp2f(x)
#endif

static __device__ __forceinline__ unsigned short f2bf(float f) {
    union { float f; unsigned int u; } v;
    v.f = f;
    unsigned int u = v.u;
    u += ((u >> 16) & 1u) + 0x7FFFu;   // RNE
    return (unsigned short)(u >> 16);
}

// hardware RNE f32->bf16 (compiler emits v_cvt_pk_bf16_f32 for pairs)
static __device__ __forceinline__ unsigned short f2bf_hw(float f) {
    __hip_bfloat16 h = __float2bfloat16(f);
    return *reinterpret_cast<unsigned short*>(&h);
}

// async global->LDS DMA, 16B per lane; LDS dest = uniform base + lane*16
static __device__ __forceinline__ void gload_lds16(const void* g, void* l) {
    __builtin_amdgcn_global_load_lds(
        (const __attribute__((address_space(1))) void*)g,
        (__attribute__((address_space(3))) void*)l, 16, 0, 0);
}

// ---------------------------------------------------------------------------
// Pre-pass 1: cast hs fp32 -> bf16. 8 elems/thread.
// ---------------------------------------------------------------------------
__global__ __launch_bounds__(256) void cast_hs(const float* __restrict__ in,
                                               unsigned short* __restrict__ out) {
    const size_t i = ((size_t)blockIdx.x * 256 + threadIdx.x) * 8;
    float4 a0 = *reinterpret_cast<const float4*>(in + i);
    float4 a1 = *reinterpret_cast<const float4*>(in + i + 4);
    unsigned short t[8];
    t[0] = f2bf(a0.x); t[1] = f2bf(a0.y); t[2] = f2bf(a0.z); t[3] = f2bf(a0.w);
    t[4] = f2bf(a1.x); t[5] = f2bf(a1.y); t[6] = f2bf(a1.z); t[7] = f2bf(a1.w);
    *reinterpret_cast<int4v*>(out + i) = *reinterpret_cast<int4v*>(t);
}

// ---------------------------------------------------------------------------
// Pre-pass 2: W[1024][1024] fp32 -> Wt[n][k] bf16 (3 slices via grid.z).
// ---------------------------------------------------------------------------
__global__ __launch_bounds__(256) void transpose_cast_w(
    const float* __restrict__ W0, const float* __restrict__ W1,
    const float* __restrict__ W2, unsigned short* __restrict__ Wt) {
    __shared__ float Ts[64][65];
    const float* W = (blockIdx.z == 0) ? W0 : (blockIdx.z == 1) ? W1 : W2;
    unsigned short* O = Wt + (size_t)blockIdx.z * 1048576;

    const int t  = threadIdx.x;
    const int k0 = blockIdx.y * 64;
    const int n0 = blockIdx.x * 64;

    {
        const int kr = t >> 2, nc = (t & 3) * 16;
        const float* p = W + (size_t)(k0 + kr) * 1024 + n0 + nc;
        float4 r0 = *reinterpret_cast<const float4*>(p);
        float4 r1 = *reinterpret_cast<const float4*>(p + 4);
        float4 r2 = *reinterpret_cast<const float4*>(p + 8);
        float4 r3 = *reinterpret_cast<const float4*>(p + 12);
        float* d = &Ts[kr][nc];
        d[0]=r0.x; d[1]=r0.y; d[2]=r0.z; d[3]=r0.w;
        d[4]=r1.x; d[5]=r1.y; d[6]=r1.z; d[7]=r1.w;
        d[8]=r2.x; d[9]=r2.y; d[10]=r2.z; d[11]=r2.w;
        d[12]=r3.x; d[13]=r3.y; d[14]=r3.z; d[15]=r3.w;
    }
    __syncthreads();
    {
        const int nr = t >> 2, kc = (t & 3) * 16;
        unsigned short tmp[16];
#pragma unroll
        for (int i = 0; i < 16; i++) tmp[i] = f2bf(Ts[kc + i][nr]);
        unsigned short* d = O + (size_t)(n0 + nr) * 1024 + k0 + kc;
        *reinterpret_cast<int4v*>(d)     = *reinterpret_cast<int4v*>(&tmp[0]);
        *reinterpret_cast<int4v*>(d + 8) = *reinterpret_cast<int4v*>(&tmp[8]);
    }
}

// ---------------------------------------------------------------------------
// Kernel 3: QKV GEMM (m97 pattern, DMA staging, 128x128, BK=32 -- proven).
// Epilogues: z=0 Q natural layout, PRE-SCALED by 0.125*log2(e);
//            z=1 K swizzled cols (d-chunk ^ (s&7));
//            z=2 V^T [B,H,dh,S] swizzled cols (s-chunk ^ (d&7)).
// ---------------------------------------------------------------------------
__global__ __launch_bounds__(256) void qkv_gemm_dma(
    const unsigned short* __restrict__ hsb,
    const unsigned short* __restrict__ Wt,
    const float* __restrict__ b0, const float* __restrict__ b1,
    const float* __restrict__ b2,
    unsigned short* __restrict__ Qo,
    unsigned short* __restrict__ Ko,
    unsigned short* __restrict__ Vto)
{
    __shared__ unsigned short As[128][32];
    __shared__ unsigned short Bs[128][32];

    const int z = blockIdx.z;
    const unsigned short* W = Wt + (size_t)z * 1048576;
    const float* bias = (z == 0) ? b0 : (z == 1) ? b1 : b2;

    const int tid  = threadIdx.x;
    const int lane = tid & 63;
    const int w    = tid >> 6;
    const int l15  = lane & 15;
    const int quad = lane >> 4;
    const int m0   = blockIdx.y * 128;
    const int n0   = blockIdx.x * 128;
    const int wm   = (w >> 1) * 64;
    const int wn   = (w & 1) * 64;

    const int drow = lane >> 2;
    const int dcol = (lane & 3) * 8;

    f32x4 acc[4][4];
#pragma unroll
    for (int i = 0; i < 4; i++)
#pragma unroll
        for (int j = 0; j < 4; j++)
            acc[i][j] = (f32x4){0.f, 0.f, 0.f, 0.f};

    for (int k0 = 0; k0 < 1024; k0 += 32) {
        __syncthreads();
#pragma unroll
        for (int p = 0; p < 2; p++) {
            const int s = w * 2 + p;
            gload_lds16(hsb + (size_t)(m0 + s * 16 + drow) * 1024 + k0 + dcol,
                        &As[s * 16][0]);
            gload_lds16(W   + (size_t)(n0 + s * 16 + drow) * 1024 + k0 + dcol,
                        &Bs[s * 16][0]);
        }
        __syncthreads();

        bf16x8 af[4], bfr[4];
#pragma unroll
        for (int i = 0; i < 4; i++)
            af[i] = *reinterpret_cast<const bf16x8*>(&As[wm + i * 16 + l15][quad * 8]);
#pragma unroll
        for (int j = 0; j < 4; j++)
            bfr[j] = *reinterpret_cast<const bf16x8*>(&Bs[wn + j * 16 + l15][quad * 8]);
#pragma unroll
        for (int i = 0; i < 4; i++)
#pragma unroll
            for (int j = 0; j < 4; j++)
                acc[i][j] = MFMA16(af[i], bfr[j], acc[i][j]);
    }

    if (z == 0) {
        // Q: natural [B,H,S,dh], pre-scaled by 0.125*log2(e)
        const float qs = 0.18033688f;
#pragma unroll
        for (int i = 0; i < 4; i++) {
            const int mbase = m0 + wm + i * 16 + quad * 4;
#pragma unroll
            for (int j = 0; j < 4; j++) {
                const int n = n0 + wn + j * 16 + l15;
                const int h = n >> 6, d = n & 63;
                const float bn = bias[n];
#pragma unroll
                for (int r = 0; r < 4; r++) {
                    const int mm = mbase + r;
                    const int b = mm >> 11, s = mm & 2047;
                    Qo[(((size_t)(b * 16 + h) * 2048 + s) * 64) + d] =
                        f2bf((acc[i][j][r] + bn) * qs);
                }
            }
        }
    } else if (z == 1) {
        // K: [B,H,S,dh] with d-chunk swizzle by (s&7)
#pragma unroll
        for (int i = 0; i < 4; i++) {
            const int mbase = m0 + wm + i * 16 + quad * 4;
#pragma unroll
            for (int j = 0; j < 4; j++) {
                const int n = n0 + wn + j * 16 + l15;
                const int h = n >> 6, d = n & 63;
                const float bn = bias[n];
#pragma unroll
                for (int r = 0; r < 4; r++) {
                    const int mm = mbase + r;
                    const int b = mm >> 11, s = mm & 2047;
                    const int dsw = ((((d >> 3) ^ (s & 7)) & 7) << 3) | (d & 7);
                    Ko[(((size_t)(b * 16 + h) * 2048 + s) * 64) + dsw] =
                        f2bf(acc[i][j][r] + bn);
                }
            }
        }
    } else {
        // V^T: [B,H,dh,S] with s-chunk swizzle by (d&7); 4 consecutive s packed
#pragma unroll
        for (int i = 0; i < 4; i++) {
            const int mbase = m0 + wm + i * 16 + quad * 4;
            const int b = mbase >> 11, s0 = mbase & 2047;
#pragma unroll
            for (int j = 0; j < 4; j++) {
                const int n = n0 + wn + j * 16 + l15;
                const int h = n >> 6, d = n & 63;
                const float bn = bias[n];
                ushort4 v4;
                v4.x = f2bf(acc[i][j][0] + bn);
                v4.y = f2bf(acc[i][j][1] + bn);
                v4.z = f2bf(acc[i][j][2] + bn);
                v4.w = f2bf(acc[i][j][3] + bn);
                const int cs  = (s0 & 63) >> 3;
                const int ssw = (s0 & ~63) | (((cs ^ (d & 7)) & 7) << 3) | (s0 & 7);
                *reinterpret_cast<ushort4*>(
                    Vto + ((size_t)(b * 16 + h) * 64 + d) * 2048 + ssw) = v4;
            }
        }
    }
}

// ---------------------------------------------------------------------------
// Kernel 4: MFMA flash attention, max-free softmax, swizzled K/V^T tiles.
// 1 block = (b,h,128 q-rows), 8 waves (R15 structure: 16 waves/CU, the
// latency-hiding sweet spot); wave w owns q-rows [16w,16w+16).
// Pipelined: K/V double-buffered, next tile's DMA issued before compute,
// one __syncthreads per tile (its vmcnt drain = prefetch completion).
// Flat grid 512, XCD-bijective: lin%8 = bh%8 -> all 16 q-blocks of a (b,h)
// on one XCD; its L2 holds K/V for 4 bh (2MB of 4MB).
// ---------------------------------------------------------------------------
__global__ __launch_bounds__(512) void attn3(
    const unsigned short* __restrict__ Qg,
    const unsigned short* __restrict__ Kg,
    const unsigned short* __restrict__ Vtg,
    float* __restrict__ out)
{
    __shared__ unsigned short Ks[2][64][64];   // [buf][kk][d] swizzled (DMA)
    __shared__ unsigned short Vs[2][64][64];   // [buf] V^T tile [d][kk] swizzled (DMA)
    __shared__ unsigned short Ps[8][16][68];   // per-wave P [qrow][kk], stride 68
                                               // (34 dw = 2 mod 32: 0 conflicts,
                                               //  measured R15)

    const int tid  = threadIdx.x;
    const int lane = tid & 63;
    const int w    = tid >> 6;        // 0..7
    const int l15  = lane & 15;
    const int quad = lane >> 4;

    // XCD-bijective decode: lin = (bh&7) + 8*qb + 128*(bh>>3)
    const int lin = blockIdx.x;               // 0..511
    const int qb  = (lin >> 3) & 15;
    const int bh  = (lin & 7) | ((lin >> 7) << 3);
    const int q0  = qb * 128;
    const size_t base = (size_t)bh * 2048 * 64;
    const unsigned short* Qh  = Qg  + base;
    const unsigned short* Kh  = Kg  + base;
    const unsigned short* Vth = Vtg + base;
    const int b = bh >> 4;
    const int h = bh & 15;

    const int drow = lane >> 3;       // 0..7
    const int dcol = (lane & 7) * 8;  // 0..56

    bf16x8 qf[2];
#pragma unroll
    for (int ks = 0; ks < 2; ks++)
        qf[ks] = *reinterpret_cast<const bf16x8*>(
            Qh + (size_t)(q0 + w * 16 + l15) * 64 + ks * 32 + quad * 8);

    f32x4 o[4];
#pragma unroll
    for (int t = 0; t < 4; t++) o[t] = (f32x4){0.f, 0.f, 0.f, 0.f};
    float rsum[4] = {0.f, 0.f, 0.f, 0.f};

    // swizzled chunk columns for frag reads (row&7 == l15&7 for 16-row tiles)
    const int c0 = (((quad + 0) ^ (l15 & 7)) & 7) * 8;   // ks=0
    const int c1 = (((quad + 4) ^ (l15 & 7)) & 7) * 8;   // ks=1

    // prologue: stage tile 0 into buffer 0 (each wave: 8 rows of K, 8 of V^T)
    gload_lds16(Kh  + (size_t)(w * 8 + drow) * 64 + dcol,   &Ks[0][w * 8][0]);
    gload_lds16(Vth + (size_t)(w * 8 + drow) * 2048 + dcol, &Vs[0][w * 8][0]);
    __syncthreads();

    int cur = 0;
    for (int kt = 0; kt < 32; kt++) {
        // issue next tile's DMA into the other buffer; it drains at the
        // end-of-iteration barrier, i.e. after a full compute phase.
        if (kt < 31) {
            const int kn = kt + 1;
            gload_lds16(Kh  + (size_t)kn * 4096 + (size_t)(w * 8 + drow) * 64 + dcol,
                        &Ks[cur ^ 1][w * 8][0]);
            gload_lds16(Vth + (size_t)(w * 8 + drow) * 2048 + kn * 64 + dcol,
                        &Vs[cur ^ 1][w * 8][0]);
        }

        const unsigned short (*Kc)[64] = Ks[cur];
        const unsigned short (*Vc)[64] = Vs[cur];

        // S = Q~ K^T (scale+ln2 folded into Q); P = exp2(S)
#pragma unroll
        for (int t = 0; t < 4; t++) {
            f32x4 sc = (f32x4){0.f, 0.f, 0.f, 0.f};
            bf16x8 kf0 = *reinterpret_cast<const bf16x8*>(&Kc[t * 16 + l15][c0]);
            bf16x8 kf1 = *reinterpret_cast<const bf16x8*>(&Kc[t * 16 + l15][c1]);
            __builtin_amdgcn_s_setprio(1);
            sc = MFMA16(qf[0], kf0, sc);
            sc = MFMA16(qf[1], kf1, sc);
            __builtin_amdgcn_s_setprio(0);
#pragma unroll
            for (int r = 0; r < 4; r++) {
                const float p = EXP2(sc[r]);
                rsum[r] += p;
                Ps[w][quad * 4 + r][t * 16 + l15] = f2bf_hw(p);
            }
        }

        // hard W->R order on wave-private Ps: drain LDS writes, forbid the
        // scheduler from hoisting the pf reads above this point.
        asm volatile("s_waitcnt lgkmcnt(0)" ::: "memory");
        __builtin_amdgcn_sched_barrier(0);

        bf16x8 pf[2];
#pragma unroll
        for (int ks = 0; ks < 2; ks++)
            pf[ks] = *reinterpret_cast<const bf16x8*>(&Ps[w][l15][ks * 32 + quad * 8]);

#pragma unroll
        for (int t = 0; t < 4; t++) {
            bf16x8 vf0 = *reinterpret_cast<const bf16x8*>(&Vc[t * 16 + l15][c0]);
            bf16x8 vf1 = *reinterpret_cast<const bf16x8*>(&Vc[t * 16 + l15][c1]);
            __builtin_amdgcn_s_setprio(1);
            o[t] = MFMA16(pf[0], vf0, o[t]);
            o[t] = MFMA16(pf[1], vf1, o[t]);
            __builtin_amdgcn_s_setprio(0);
        }

        __syncthreads();   // drains next tile's DMA + guards buffer reuse
        cur ^= 1;
    }

    // deferred l reduction: row quad*4+r spread over 16 lanes sharing quad
#pragma unroll
    for (int off = 1; off < 16; off <<= 1)
#pragma unroll
        for (int r = 0; r < 4; r++)
            rsum[r] += __shfl_xor(rsum[r], off, 64);

    // epilogue: out[b][q][h*64+d], fp32
#pragma unroll
    for (int t = 0; t < 4; t++) {
#pragma unroll
        for (int r = 0; r < 4; r++) {
            const int q = q0 + w * 16 + quad * 4 + r;
            const size_t oidx = (((size_t)b * 2048 + q) * 16 + h) * 64 + t * 16 + l15;
            out[oidx] = o[t][r] / rsum[r];
        }
    }
}

// ---------------------------------------------------------------------------
__global__ void fill_sentinel(float* out, int n, float pat) {
    int i = blockIdx.x * blockDim.x + threadIdx.x;
    if (i < n) out[i] = pat;
}

// ---------------------------------------------------------------------------
extern "C" void kernel_launch(void* const* d_in, const int* in_sizes, int n_in,
                              void* d_out, int out_size, void* d_ws, size_t ws_size,
                              hipStream_t stream) {
    const size_t n_hs  = (size_t)4096 * 1024;
    const size_t n_w   = (size_t)1024 * 1024;
    const size_t n_qkv = n_hs;
    const size_t need = (n_hs + 3 * n_w + 3 * n_qkv) * sizeof(unsigned short);

    bool order_ok = (n_in == 7) &&
        in_sizes[0] == 4194304 &&
        in_sizes[1] == 1048576 && in_sizes[2] == 1024 &&
        in_sizes[3] == 1048576 && in_sizes[4] == 1024 &&
        in_sizes[5] == 1048576 && in_sizes[6] == 1024;
    if (!order_ok || out_size != 4194304) {
        fill_sentinel<<<(out_size + 255) / 256, 256, 0, stream>>>(
            (float*)d_out, out_size, 4.0f);
        return;
    }
    if (ws_size < need) {
        fill_sentinel<<<(out_size + 255) / 256, 256, 0, stream>>>(
            (float*)d_out, out_size, 2.0f);
        return;
    }

    const float* hs = (const float*)d_in[0];
    const float* Wq = (const float*)d_in[1];
    const float* bq = (const float*)d_in[2];
    const float* Wk = (const float*)d_in[3];
    const float* bk = (const float*)d_in[4];
    const float* Wv = (const float*)d_in[5];
    const float* bv = (const float*)d_in[6];

    unsigned short* hsb = (unsigned short*)d_ws;
    unsigned short* Wt  = hsb + n_hs;
    unsigned short* Q   = Wt + 3 * n_w;
    unsigned short* K   = Q + n_qkv;
    unsigned short* Vt  = K + n_qkv;

    cast_hs<<<2048, 256, 0, stream>>>(hs, hsb);
    transpose_cast_w<<<dim3(16, 16, 3), 256, 0, stream>>>(Wq, Wk, Wv, Wt);

    dim3 g1(8, 32, 3);    // (N/128, M/128, {q,k,v})
    qkv_gemm_dma<<<g1, dim3(256), 0, stream>>>(hsb, Wt, bq, bk, bv, Q, K, Vt);

    attn3<<<dim3(512), dim3(512), 0, stream>>>(Q, K, Vt, (float*)d_out);
}